// Round 15
// baseline (640.690 us; speedup 1.0000x reference)
//
#include <hip/hip_runtime.h>
#include <hip/hip_fp16.h>
#include <hip/hip_cooperative_groups.h>

namespace cg = cooperative_groups;

#define N_NODES 50000
#define N_EDGES 800000
#define N_FEAT 128
#define HIDDEN 64
#define N_CLASSES 16
#define NT 196          // 256-node dst tiles (R12 best config)
#define TCAP 8192       // per-tile bucket capacity; mean 4083, sigma ~64
#define NCHUNK 782      // ceil(800000/1024) edge chunks for the partition phase
#define SMEM_BYTES 35840

typedef _Float16 f16x8 __attribute__((ext_vector_type(8)));
typedef float f32x4 __attribute__((ext_vector_type(4)));

// add one fp16 row-octet (int4 = 8 halves) into fp32 accumulators
__device__ __forceinline__ void acc_row8(float* a, int4 rv) {
    float2 f;
    f = __half22float2(*(__half2*)&rv.x); a[0] += f.x; a[1] += f.y;
    f = __half22float2(*(__half2*)&rv.y); a[2] += f.x; a[3] += f.y;
    f = __half22float2(*(__half2*)&rv.z); a[4] += f.x; a[5] += f.y;
    f = __half22float2(*(__half2*)&rv.w); a[6] += f.x; a[7] += f.y;
}

// octet-scheme gather for one node (one wave): pure row-sum of pre-scaled rows,
// then relu(dinv*sum + b) stored fp16. lane = {edge slot e8, feature octet q}.
__device__ __forceinline__ void gather_node(const __half* __restrict__ h,
                                            const int* __restrict__ csr,
                                            const int2* __restrict__ rse,
                                            const float* __restrict__ dinv,
                                            const float* __restrict__ bias,
                                            __half* __restrict__ out,
                                            int node, int e8, int q) {
    int2 se = rse[node];
    int r0 = se.x, r1 = se.x + se.y;
    float dd = dinv[node];
    float a[8] = {0.f, 0.f, 0.f, 0.f, 0.f, 0.f, 0.f, 0.f};
    if (e8 == 0)  // self-loop row counted once
        acc_row8(a, *(const int4*)&h[(long)node * HIDDEN + q * 8]);
    int j = r0;
    while (j + 16 <= r1) {
        int sA = csr[j + e8];
        int sB = csr[j + 8 + e8];
        int4 rA = *(const int4*)&h[(long)sA * HIDDEN + q * 8];
        int4 rB = *(const int4*)&h[(long)sB * HIDDEN + q * 8];
        acc_row8(a, rA);
        acc_row8(a, rB);
        j += 16;
    }
    if (j + 8 <= r1) {
        int sA = csr[j + e8];
        acc_row8(a, *(const int4*)&h[(long)sA * HIDDEN + q * 8]);
        j += 8;
    }
    int rem = r1 - j;
    if (e8 < rem) {
        int sA = csr[j + e8];
        acc_row8(a, *(const int4*)&h[(long)sA * HIDDEN + q * 8]);
    }
#pragma unroll
    for (int off = 8; off < 64; off <<= 1)
#pragma unroll
        for (int i = 0; i < 8; ++i) a[i] += __shfl_xor(a[i], off, 64);

    if (e8 == 0) {
        float4 b0 = *(const float4*)&bias[q * 8];
        float4 b1 = *(const float4*)&bias[q * 8 + 4];
        float r[8];
        r[0] = fmaxf(fmaf(a[0], dd, b0.x), 0.f);
        r[1] = fmaxf(fmaf(a[1], dd, b0.y), 0.f);
        r[2] = fmaxf(fmaf(a[2], dd, b0.z), 0.f);
        r[3] = fmaxf(fmaf(a[3], dd, b0.w), 0.f);
        r[4] = fmaxf(fmaf(a[4], dd, b1.x), 0.f);
        r[5] = fmaxf(fmaf(a[5], dd, b1.y), 0.f);
        r[6] = fmaxf(fmaf(a[6], dd, b1.z), 0.f);
        r[7] = fmaxf(fmaf(a[7], dd, b1.w), 0.f);
        __half2 h0 = __floats2half2_rn(r[0], r[1]);
        __half2 h1 = __floats2half2_rn(r[2], r[3]);
        __half2 h2 = __floats2half2_rn(r[4], r[5]);
        __half2 h3 = __floats2half2_rn(r[6], r[7]);
        int4 o;
        o.x = *(int*)&h0; o.y = *(int*)&h1; o.z = *(int*)&h2; o.w = *(int*)&h3;
        *(int4*)&out[(long)node * HIDDEN + q * 8] = o;
    }
}

// MFMA GEMM phase: out[n,f] = (A @ W)[n,f] * dinv[n], fp16 out. W staged once
// per block; grid-stride over 64-node tiles. Verified 16x16x32_f16 layouts.
template <int K, typename TIn>
__device__ __forceinline__ void mm_phase(const TIn* __restrict__ a,
                                         const float* __restrict__ w,
                                         const float* __restrict__ dinv,
                                         __half* __restrict__ out,
                                         int bid, int nB, char* smem) {
    constexpr int LDK = K + 8;
    __half* A_lds = (__half*)smem;                       // 64*LDK halves
    __half* Wt_lds = (__half*)(smem + 64 * LDK * 2);     // 64*LDK halves
    int tid = threadIdx.x;
    for (int i = tid; i < K * 16; i += 256) {
        int k = (i * 4) >> 6;
        int f0 = (i * 4) & 63;
        float4 v = *(const float4*)&w[i * 4];
        Wt_lds[(f0 + 0) * LDK + k] = __float2half(v.x);
        Wt_lds[(f0 + 1) * LDK + k] = __float2half(v.y);
        Wt_lds[(f0 + 2) * LDK + k] = __float2half(v.z);
        Wt_lds[(f0 + 3) * LDK + k] = __float2half(v.w);
    }
    int wv = tid >> 6;
    int lane = tid & 63;
    int mr = lane & 15;
    int quad = lane >> 4;
    for (int tile = bid; tile < (N_NODES + 63) / 64; tile += nB) {
        __syncthreads();  // covers W visibility (1st iter) + A_lds reuse (later)
        long nbase = (long)tile * 64;
        for (int i = tid; i < 64 * K / 8; i += 256) {
            int n = (i * 8) / K;
            int k0 = (i * 8) % K;
            long gn = nbase + n;
            if constexpr (sizeof(TIn) == 4) {
                float4 v0, v1;
                if (gn < N_NODES) {
                    v0 = *(const float4*)&a[gn * K + k0];
                    v1 = *(const float4*)&a[gn * K + k0 + 4];
                } else {
                    v0 = make_float4(0.f, 0.f, 0.f, 0.f);
                    v1 = v0;
                }
                __half2* dst = (__half2*)&A_lds[n * LDK + k0];
                dst[0] = __floats2half2_rn(v0.x, v0.y);
                dst[1] = __floats2half2_rn(v0.z, v0.w);
                dst[2] = __floats2half2_rn(v1.x, v1.y);
                dst[3] = __floats2half2_rn(v1.z, v1.w);
            } else {
                int4 v = (gn < N_NODES) ? *(const int4*)&a[gn * K + k0]
                                        : make_int4(0, 0, 0, 0);
                *(int4*)&A_lds[n * LDK + k0] = v;
            }
        }
        __syncthreads();
        const __half* Arow = &A_lds[(wv * 16 + mr) * LDK + quad * 8];
        f32x4 acc[4] = {};
#pragma unroll
        for (int t = 0; t < K; t += 32) {
            f16x8 af = *(const f16x8*)(const void*)&Arow[t];
#pragma unroll
            for (int g = 0; g < 4; ++g) {
                f16x8 bf = *(const f16x8*)(const void*)&Wt_lds[(g * 16 + mr) * LDK + t + quad * 8];
                acc[g] = __builtin_amdgcn_mfma_f32_16x16x32_f16(af, bf, acc[g], 0, 0, 0);
            }
        }
#pragma unroll
        for (int r = 0; r < 4; ++r) {
            int n = wv * 16 + quad * 4 + r;
            long gn = nbase + n;
            if (gn < N_NODES) {
                float di = dinv[gn];
#pragma unroll
                for (int g = 0; g < 4; ++g)
                    out[gn * HIDDEN + g * 16 + mr] = __float2half(acc[g][r] * di);
            }
        }
    }
}

// ---- the whole GCN as ONE cooperative kernel: 8 phases, 7 grid syncs ----
__global__ __launch_bounds__(256, 4) void mega(
    const float* __restrict__ x, const int* __restrict__ ei,
    const float* __restrict__ W1, const float* __restrict__ b1,
    const float* __restrict__ W2, const float* __restrict__ b2,
    const float* __restrict__ Wout, const float* __restrict__ bout,
    float* __restrict__ out,
    int* __restrict__ tileCur, int* __restrict__ binned, int* __restrict__ csr,
    int2* __restrict__ rse, float* __restrict__ dinv,
    __half* __restrict__ bufA, __half* __restrict__ bufB) {
    cg::grid_group grid = cg::this_grid();
    __shared__ __align__(16) char smem[SMEM_BYTES];
    int tid = threadIdx.x;
    int bid = blockIdx.x;
    int nB = gridDim.x;

    // ---- phase 0: bucket cursors ----
    for (int i = bid * 256 + tid; i < NT; i += nB * 256) tileCur[i] = i * TCAP;
    grid.sync();

    // ---- phase 1: partition edges into 196 dst-tile buckets ----
    {
        int* cnt = (int*)smem;
        int* base = cnt + NT;
        int* cur = base + NT;
        for (int cb = bid; cb < NCHUNK; cb += nB) {
            if (tid < NT) cnt[tid] = 0;
            __syncthreads();
            int s[4], d[4];
            int e0 = cb * 1024 + tid * 4;
            if (e0 + 4 <= N_EDGES) {
                int4 s4 = *(const int4*)&ei[e0];
                int4 d4 = *(const int4*)&ei[N_EDGES + e0];
                s[0] = s4.x; s[1] = s4.y; s[2] = s4.z; s[3] = s4.w;
                d[0] = d4.x; d[1] = d4.y; d[2] = d4.z; d[3] = d4.w;
#pragma unroll
                for (int u = 0; u < 4; ++u) atomicAdd(&cnt[d[u] >> 8], 1);
            } else {
#pragma unroll
                for (int u = 0; u < 4; ++u) {
                    int e = e0 + u;
                    if (e < N_EDGES) {
                        s[u] = ei[e];
                        d[u] = ei[N_EDGES + e];
                        atomicAdd(&cnt[d[u] >> 8], 1);
                    } else s[u] = -1;
                }
            }
            __syncthreads();
            if (tid < NT) {
                base[tid] = atomicAdd(&tileCur[tid], cnt[tid]);
                cur[tid] = 0;
            }
            __syncthreads();
#pragma unroll
            for (int u = 0; u < 4; ++u) {
                if (s[u] < 0) continue;
                int t = d[u] >> 8;
                int r = atomicAdd(&cur[t], 1);
                int p = base[t] + r;
                if (p >= t * TCAP && p < (t + 1) * TCAP)
                    binned[p] = s[u] | ((d[u] & 255) << 16);
            }
            __syncthreads();  // protect base/cur before next iteration
        }
    }
    grid.sync();

    // ---- phase 2: per-tile counting sort + degree -> dinv + rse ----
    {
        int* stage = (int*)smem;                      // TCAP ints
        int* cnt256 = (int*)(smem + TCAP * 4);        // 256
        int* sc = cnt256 + 256;                       // 256
        int* nodeOff = sc + 256;                      // 256
        for (int tb = bid; tb < NT; tb += nB) {
            int beg = tb * TCAP;
            int m = tileCur[tb] - beg;
            if (m > TCAP) m = TCAP;
            if (m < 0) m = 0;
            cnt256[tid] = 0;
            __syncthreads();
            const int4* b4 = (const int4*)(binned + beg);
            int nv = m >> 2;
            for (int i = tid; i < nv; i += 256) {
                int4 r = b4[i];
                atomicAdd(&cnt256[(r.x >> 16) & 255], 1);
                atomicAdd(&cnt256[(r.y >> 16) & 255], 1);
                atomicAdd(&cnt256[(r.z >> 16) & 255], 1);
                atomicAdd(&cnt256[(r.w >> 16) & 255], 1);
            }
            for (int i = (m & ~3) + tid; i < m; i += 256)
                atomicAdd(&cnt256[(binned[beg + i] >> 16) & 255], 1);
            __syncthreads();
            int myc = cnt256[tid];
            sc[tid] = myc;
            __syncthreads();
#pragma unroll
            for (int off = 1; off < 256; off <<= 1) {
                int t = (tid >= off) ? sc[tid - off] : 0;
                __syncthreads();
                sc[tid] += t;
                __syncthreads();
            }
            int off0 = sc[tid] - myc;
            nodeOff[tid] = off0;
            int gnode = tb * 256 + tid;
            if (gnode < N_NODES) {
                dinv[gnode] = rsqrtf((float)myc + 1.0f);
                rse[gnode] = make_int2(beg + off0, myc);
            }
            cnt256[tid] = 0;
            __syncthreads();
            for (int i = tid; i < nv; i += 256) {
                int4 r = b4[i];
                int rr;
                rr = atomicAdd(&cnt256[(r.x >> 16) & 255], 1); stage[nodeOff[(r.x >> 16) & 255] + rr] = r.x & 0xFFFF;
                rr = atomicAdd(&cnt256[(r.y >> 16) & 255], 1); stage[nodeOff[(r.y >> 16) & 255] + rr] = r.y & 0xFFFF;
                rr = atomicAdd(&cnt256[(r.z >> 16) & 255], 1); stage[nodeOff[(r.z >> 16) & 255] + rr] = r.z & 0xFFFF;
                rr = atomicAdd(&cnt256[(r.w >> 16) & 255], 1); stage[nodeOff[(r.w >> 16) & 255] + rr] = r.w & 0xFFFF;
            }
            for (int i = (m & ~3) + tid; i < m; i += 256) {
                int rec = binned[beg + i];
                int dl = (rec >> 16) & 255;
                int rr = atomicAdd(&cnt256[dl], 1);
                stage[nodeOff[dl] + rr] = rec & 0xFFFF;
            }
            __syncthreads();
            int4* c4 = (int4*)(csr + beg);
            for (int i = tid; i < nv; i += 256) c4[i] = ((const int4*)stage)[i];
            for (int i = (m & ~3) + tid; i < m; i += 256) csr[beg + i] = stage[i];
            __syncthreads();  // protect stage before next iteration
        }
    }
    grid.sync();

    // ---- phase 3: H1' = (X @ W1) * dinv (binned buffer dies; bufA born) ----
    mm_phase<N_FEAT, float>(x, W1, dinv, bufA, bid, nB, smem);
    grid.sync();

    // ---- phase 4: gather layer 1 -> bufB ----
    {
        int wv = tid >> 6;
        int lane = tid & 63;
        int e8 = lane >> 3, q = lane & 7;
        for (int vb = bid; vb < N_NODES / 4; vb += nB) {
            int node = __builtin_amdgcn_readfirstlane(vb * 4 + wv);
            gather_node(bufA, csr, rse, dinv, b1, bufB, node, e8, q);
        }
    }
    grid.sync();

    // ---- phase 5: H2' = (H1a @ W2) * dinv -> bufA ----
    mm_phase<HIDDEN, __half>(bufB, W2, dinv, bufA, bid, nB, smem);
    grid.sync();

    // ---- phase 6: gather layer 2 -> bufB ----
    {
        int wv = tid >> 6;
        int lane = tid & 63;
        int e8 = lane >> 3, q = lane & 7;
        for (int vb = bid; vb < N_NODES / 4; vb += nB) {
            int node = __builtin_amdgcn_readfirstlane(vb * 4 + wv);
            gather_node(bufA, csr, rse, dinv, b2, bufB, node, e8, q);
        }
    }
    grid.sync();

    // ---- phase 7: logits + softmax ----
    {
        float* Ws = (float*)smem;                 // 64*16 fp32
        float* bs = Ws + HIDDEN * N_CLASSES;
        for (int i = tid; i < HIDDEN * N_CLASSES; i += 256) Ws[i] = Wout[i];
        if (tid < N_CLASSES) bs[tid] = bout[tid];
        __syncthreads();
        int c = tid & 15;
        int sub = tid >> 4;
        for (int g = bid; g < N_NODES / 16; g += nB) {
            int node = g * 16 + sub;
            const __half* hr = bufB + (long)node * HIDDEN;
            float acc = bs[c];
#pragma unroll
            for (int k = 0; k < HIDDEN; ++k)
                acc = fmaf(__half2float(hr[k]), Ws[k * N_CLASSES + c], acc);
            float m2 = acc;
#pragma unroll
            for (int off = 8; off; off >>= 1) m2 = fmaxf(m2, __shfl_xor(m2, off, 16));
            float ex = expf(acc - m2);
            float s = ex;
#pragma unroll
            for (int off = 8; off; off >>= 1) s += __shfl_xor(s, off, 16);
            out[(long)node * N_CLASSES + c] = ex / s;
        }
    }
}

extern "C" void kernel_launch(void* const* d_in, const int* in_sizes, int n_in,
                              void* d_out, int out_size, void* d_ws, size_t ws_size,
                              hipStream_t stream) {
    const float* x    = (const float*)d_in[0];
    const int*   ei   = (const int*)d_in[1];
    const float* W1   = (const float*)d_in[2];
    const float* b1   = (const float*)d_in[3];
    const float* W2   = (const float*)d_in[4];
    const float* b2   = (const float*)d_in[5];
    const float* Wout = (const float*)d_in[6];
    const float* bout = (const float*)d_in[7];
    float* out = (float*)d_out;

    char* ws = (char*)d_ws;
    int2*   rse     = (int2*)ws;                       ws += 400128;   // 50000 int2
    float*  dinv    = (float*)ws;                      ws += 200192;   // 50000 f32
    int*    tileCur = (int*)ws;                        ws += 1024;
    int*    csr     = (int*)ws;                        ws += (size_t)NT * TCAP * 4;  // 6.42 MB
    char*   slotA   = ws;                              ws += 6553600;  // max(binned, bufA)
    __half* bufB    = (__half*)ws;
    int*    binned  = (int*)slotA;   // lives phases 1-2; bufA born phase 3
    __half* bufA    = (__half*)slotA;

    int maxb = 0;
    if (hipOccupancyMaxActiveBlocksPerMultiprocessor(&maxb, mega, 256, 0) != hipSuccess || maxb < 1)
        maxb = 2;  // conservative fallback; same work either way
    if (maxb > 8) maxb = 8;
    int G = maxb * 256;  // MI355X: 256 CUs; grid guaranteed co-resident

    void* kargs[] = {
        (void*)&x, (void*)&ei, (void*)&W1, (void*)&b1, (void*)&W2, (void*)&b2,
        (void*)&Wout, (void*)&bout, (void*)&out,
        (void*)&tileCur, (void*)&binned, (void*)&csr,
        (void*)&rse, (void*)&dinv, (void*)&bufA, (void*)&bufB};
    hipLaunchCooperativeKernel(mega, dim3(G), dim3(256), kargs, 0, stream);
}

// Round 16
// 172.727 us; speedup vs baseline: 3.7093x; 3.7093x over previous
//
#include <hip/hip_runtime.h>
#include <hip/hip_fp16.h>

#define N_NODES 50000
#define N_EDGES 800000
#define N_FEAT 128
#define HIDDEN 64
#define N_CLASSES 16
#define NBLK_NODE 196   // number of 256-node dst tiles (ceil(50000/256))
#define TCAP 8192       // per-tile bucket capacity (recs); mean 4083, sigma ~64

typedef _Float16 f16x8 __attribute__((ext_vector_type(8)));
typedef float f32x4 __attribute__((ext_vector_type(4)));

// tileCur[t] = t*TCAP (bucket base cursors); NBLK_NODE=196 < 256 so one block
__global__ void k_init(int* __restrict__ tileCur) {
    int tid = threadIdx.x;
    if (tid < NBLK_NODE) tileCur[tid] = tid * TCAP;
}

// Partition edges into 196 fixed-capacity dst-tile buckets. Per block: LDS
// histogram, ONE global atomic per (block,tile) reserves a contiguous sub-run
// -> block-owned 4B record stores merge in L2. record: src | dstLocal<<16
__global__ __launch_bounds__(256) void k_part(const int* __restrict__ ei,
                                              int* __restrict__ tileCur,
                                              int* __restrict__ binned) {
    __shared__ int cnt[NBLK_NODE], base[NBLK_NODE], cur[NBLK_NODE];
    int tid = threadIdx.x;
    int start = blockIdx.x * 4096;
    if (tid < NBLK_NODE) cnt[tid] = 0;
    __syncthreads();
    int s[16], d[16];
#pragma unroll
    for (int u = 0; u < 4; ++u) {
        int e0 = start + u * 1024 + tid * 4;
        if (e0 + 4 <= N_EDGES) {
            int4 s4 = *(const int4*)&ei[e0];
            int4 d4 = *(const int4*)&ei[N_EDGES + e0];
            s[u * 4 + 0] = s4.x; s[u * 4 + 1] = s4.y; s[u * 4 + 2] = s4.z; s[u * 4 + 3] = s4.w;
            d[u * 4 + 0] = d4.x; d[u * 4 + 1] = d4.y; d[u * 4 + 2] = d4.z; d[u * 4 + 3] = d4.w;
#pragma unroll
            for (int q = 0; q < 4; ++q) atomicAdd(&cnt[d[u * 4 + q] >> 8], 1);
        } else {
#pragma unroll
            for (int q = 0; q < 4; ++q) {
                int e = e0 + q;
                if (e < N_EDGES) {
                    s[u * 4 + q] = ei[e];
                    d[u * 4 + q] = ei[N_EDGES + e];
                    atomicAdd(&cnt[d[u * 4 + q] >> 8], 1);
                } else s[u * 4 + q] = -1;
            }
        }
    }
    __syncthreads();
    if (tid < NBLK_NODE) {
        base[tid] = atomicAdd(&tileCur[tid], cnt[tid]);
        cur[tid] = 0;
    }
    __syncthreads();
#pragma unroll
    for (int u = 0; u < 16; ++u) {
        if (s[u] < 0) continue;
        int t = d[u] >> 8;
        int r = atomicAdd(&cur[t], 1);
        int p = base[t] + r;
        if (p >= t * TCAP && p < (t + 1) * TCAP)  // bucket-bound guard
            binned[p] = s[u] | ((d[u] & 255) << 16);
    }
}

// Per-tile counting sort (bucketed layout). Also derives degree -> dinv and
// per-node {start,count} rse. Fully LDS-staged; coalesced int4 csr writes.
__global__ __launch_bounds__(256) void k_finesort(const int* __restrict__ binned,
                                                  const int* __restrict__ tileCur,
                                                  int* __restrict__ csr,
                                                  int2* __restrict__ rse,
                                                  float* __restrict__ dinv) {
    __shared__ int stage[TCAP];
    __shared__ int sc[256];
    __shared__ int cnt256[256];
    __shared__ int nodeOff[256];
    int tid = threadIdx.x;
    int tb = blockIdx.x;
    int beg = tb * TCAP;
    int m = tileCur[tb] - beg;
    if (m > TCAP) m = TCAP;
    if (m < 0) m = 0;
    cnt256[tid] = 0;
    __syncthreads();
    const int4* b4 = (const int4*)(binned + beg);
    int nv = m >> 2;
    for (int i = tid; i < nv; i += 256) {
        int4 r = b4[i];
        atomicAdd(&cnt256[(r.x >> 16) & 255], 1);
        atomicAdd(&cnt256[(r.y >> 16) & 255], 1);
        atomicAdd(&cnt256[(r.z >> 16) & 255], 1);
        atomicAdd(&cnt256[(r.w >> 16) & 255], 1);
    }
    for (int i = (m & ~3) + tid; i < m; i += 256)
        atomicAdd(&cnt256[(binned[beg + i] >> 16) & 255], 1);
    __syncthreads();
    int myc = cnt256[tid];
    sc[tid] = myc;
    __syncthreads();
#pragma unroll
    for (int off = 1; off < 256; off <<= 1) {
        int t = (tid >= off) ? sc[tid - off] : 0;
        __syncthreads();
        sc[tid] += t;
        __syncthreads();
    }
    int off0 = sc[tid] - myc;
    nodeOff[tid] = off0;
    int gnode = tb * 256 + tid;
    if (gnode < N_NODES) {
        dinv[gnode] = rsqrtf((float)myc + 1.0f);  // deg = in-edges + self-loop
        rse[gnode] = make_int2(beg + off0, myc);
    }
    cnt256[tid] = 0;
    __syncthreads();
    for (int i = tid; i < nv; i += 256) {
        int4 r = b4[i];
        int rr;
        rr = atomicAdd(&cnt256[(r.x >> 16) & 255], 1); stage[nodeOff[(r.x >> 16) & 255] + rr] = r.x & 0xFFFF;
        rr = atomicAdd(&cnt256[(r.y >> 16) & 255], 1); stage[nodeOff[(r.y >> 16) & 255] + rr] = r.y & 0xFFFF;
        rr = atomicAdd(&cnt256[(r.z >> 16) & 255], 1); stage[nodeOff[(r.z >> 16) & 255] + rr] = r.z & 0xFFFF;
        rr = atomicAdd(&cnt256[(r.w >> 16) & 255], 1); stage[nodeOff[(r.w >> 16) & 255] + rr] = r.w & 0xFFFF;
    }
    for (int i = (m & ~3) + tid; i < m; i += 256) {
        int rec = binned[beg + i];
        int dl = (rec >> 16) & 255;
        int rr = atomicAdd(&cnt256[dl], 1);
        stage[nodeOff[dl] + rr] = rec & 0xFFFF;
    }
    __syncthreads();
    int4* c4 = (int4*)(csr + beg);
    for (int i = tid; i < nv; i += 256) c4[i] = ((const int4*)stage)[i];
    for (int i = (m & ~3) + tid; i < m; i += 256) csr[beg + i] = stage[i];
}

// ---- MFMA GEMM: out[n,f] = (A @ W)[n,f] * dinv[n], fp16 out ----
// Block = 256 thr = 4 waves = 64 nodes; wave w covers nodes nbase+16w..+15.
// mfma_f32_16x16x32_f16; verified fragment layouts (learn_hip m89/m91).
template <int K, typename TIn>
__global__ __launch_bounds__(256) void k_mm(const TIn* __restrict__ a,
                                            const float* __restrict__ w,
                                            const float* __restrict__ dinv,
                                            __half* __restrict__ out) {
    constexpr int LDK = K + 8;
    __shared__ __align__(16) __half A_lds[64 * LDK];
    __shared__ __align__(16) __half Wt_lds[64 * LDK];
    int tid = threadIdx.x;
    long nbase = (long)blockIdx.x * 64;

    // stage W transposed: w[k*64+f] (fp32) -> Wt_lds[f][k] (fp16)
    for (int i = tid; i < K * 16; i += 256) {
        int k = (i * 4) >> 6;
        int f0 = (i * 4) & 63;
        float4 v = *(const float4*)&w[i * 4];
        Wt_lds[(f0 + 0) * LDK + k] = __float2half(v.x);
        Wt_lds[(f0 + 1) * LDK + k] = __float2half(v.y);
        Wt_lds[(f0 + 2) * LDK + k] = __float2half(v.z);
        Wt_lds[(f0 + 3) * LDK + k] = __float2half(v.w);
    }
    // stage A rows -> A_lds[n][k] fp16 (8-elem chunks)
    for (int i = tid; i < 64 * K / 8; i += 256) {
        int n = (i * 8) / K;
        int k0 = (i * 8) % K;
        long gn = nbase + n;
        if constexpr (sizeof(TIn) == 4) {
            float4 v0, v1;
            if (gn < N_NODES) {
                v0 = *(const float4*)&a[gn * K + k0];
                v1 = *(const float4*)&a[gn * K + k0 + 4];
            } else {
                v0 = make_float4(0.f, 0.f, 0.f, 0.f);
                v1 = v0;
            }
            __half2* dst = (__half2*)&A_lds[n * LDK + k0];
            dst[0] = __floats2half2_rn(v0.x, v0.y);
            dst[1] = __floats2half2_rn(v0.z, v0.w);
            dst[2] = __floats2half2_rn(v1.x, v1.y);
            dst[3] = __floats2half2_rn(v1.z, v1.w);
        } else {
            int4 v = (gn < N_NODES) ? *(const int4*)&a[gn * K + k0]
                                    : make_int4(0, 0, 0, 0);
            *(int4*)&A_lds[n * LDK + k0] = v;
        }
    }
    __syncthreads();

    int wv = tid >> 6;
    int lane = tid & 63;
    int m = lane & 15;      // A row within wave tile / D col
    int quad = lane >> 4;   // 0..3
    const __half* Arow = &A_lds[(wv * 16 + m) * LDK + quad * 8];
    f32x4 acc[4] = {};      // 4 feature col-tiles of 16
#pragma unroll
    for (int t = 0; t < K; t += 32) {
        f16x8 af = *(const f16x8*)(const void*)&Arow[t];
#pragma unroll
        for (int g = 0; g < 4; ++g) {
            f16x8 bf = *(const f16x8*)(const void*)&Wt_lds[(g * 16 + m) * LDK + t + quad * 8];
            acc[g] = __builtin_amdgcn_mfma_f32_16x16x32_f16(af, bf, acc[g], 0, 0, 0);
        }
    }

    // D: row(node) = quad*4 + r, col(feat) = g*16 + m
#pragma unroll
    for (int r = 0; r < 4; ++r) {
        int n = wv * 16 + quad * 4 + r;
        long gn = nbase + n;
        if (gn < N_NODES) {
            float di = dinv[gn];
#pragma unroll
            for (int g = 0; g < 4; ++g)
                out[gn * HIDDEN + g * 16 + m] = __float2half(acc[g][r] * di);
        }
    }
}

// add one fp16 row-octet (int4 = 8 halves) into fp32 accumulators
__device__ __forceinline__ void acc_row8(float* a, int4 rv) {
    float2 f;
    f = __half22float2(*(__half2*)&rv.x); a[0] += f.x; a[1] += f.y;
    f = __half22float2(*(__half2*)&rv.y); a[2] += f.x; a[3] += f.y;
    f = __half22float2(*(__half2*)&rv.z); a[4] += f.x; a[5] += f.y;
    f = __half22float2(*(__half2*)&rv.w); a[6] += f.x; a[7] += f.y;
}

// ---- fused aggregation on pre-scaled rows: pure row-sum, OCTET scheme ----
// out[d,:] = relu( dinv[d] * (sum_e h'[src] + h'[d]) + b )
// One wave per node. lane = {edge slot e8 = lane>>3, feature octet q = lane&7}.
__global__ void k_gather(const __half* __restrict__ h, const int* __restrict__ csr,
                         const int2* __restrict__ rse, const float* __restrict__ dinv,
                         const float* __restrict__ bias, __half* __restrict__ out) {
    int t = blockIdx.x * 256 + threadIdx.x;
    int node = __builtin_amdgcn_readfirstlane(t >> 6);  // wave-uniform
    int lane = t & 63;
    int e8 = lane >> 3;   // edge slot 0..7
    int q = lane & 7;     // features q*8 .. q*8+7
    int2 se = rse[node];
    int r0 = se.x, r1 = se.x + se.y;
    float dd = dinv[node];

    float a[8] = {0.f, 0.f, 0.f, 0.f, 0.f, 0.f, 0.f, 0.f};
    if (e8 == 0)  // self-loop row counted once
        acc_row8(a, *(const int4*)&h[(long)node * HIDDEN + q * 8]);

    int j = r0;
    while (j + 16 <= r1) {  // 16 edges: 2 independent 8-row batches in flight
        int sA = csr[j + e8];
        int sB = csr[j + 8 + e8];
        int4 rA = *(const int4*)&h[(long)sA * HIDDEN + q * 8];
        int4 rB = *(const int4*)&h[(long)sB * HIDDEN + q * 8];
        acc_row8(a, rA);
        acc_row8(a, rB);
        j += 16;
    }
    if (j + 8 <= r1) {
        int sA = csr[j + e8];
        acc_row8(a, *(const int4*)&h[(long)sA * HIDDEN + q * 8]);
        j += 8;
    }
    int rem = r1 - j;  // 0..7
    if (e8 < rem) {
        int sA = csr[j + e8];
        acc_row8(a, *(const int4*)&h[(long)sA * HIDDEN + q * 8]);
    }
    // reduce across the 8 edge slots
#pragma unroll
    for (int off = 8; off < 64; off <<= 1)
#pragma unroll
        for (int i = 0; i < 8; ++i) a[i] += __shfl_xor(a[i], off, 64);

    if (e8 == 0) {
        float4 b0 = *(const float4*)&bias[q * 8];
        float4 b1 = *(const float4*)&bias[q * 8 + 4];
        float r[8];
        r[0] = fmaxf(fmaf(a[0], dd, b0.x), 0.f);
        r[1] = fmaxf(fmaf(a[1], dd, b0.y), 0.f);
        r[2] = fmaxf(fmaf(a[2], dd, b0.z), 0.f);
        r[3] = fmaxf(fmaf(a[3], dd, b0.w), 0.f);
        r[4] = fmaxf(fmaf(a[4], dd, b1.x), 0.f);
        r[5] = fmaxf(fmaf(a[5], dd, b1.y), 0.f);
        r[6] = fmaxf(fmaf(a[6], dd, b1.z), 0.f);
        r[7] = fmaxf(fmaf(a[7], dd, b1.w), 0.f);
        __half2 h0 = __floats2half2_rn(r[0], r[1]);
        __half2 h1 = __floats2half2_rn(r[2], r[3]);
        __half2 h2 = __floats2half2_rn(r[4], r[5]);
        __half2 h3 = __floats2half2_rn(r[6], r[7]);
        int4 o;
        o.x = *(int*)&h0; o.y = *(int*)&h1; o.z = *(int*)&h2; o.w = *(int*)&h3;
        *(int4*)&out[(long)node * HIDDEN + q * 8] = o;
    }
}

// ---- logits = h @ Wout + bout, softmax over 16 classes (fp32 math) ----
__global__ void k_out(const __half* __restrict__ h, const float* __restrict__ w,
                      const float* __restrict__ b, float* __restrict__ out) {
    __shared__ float Ws[HIDDEN * N_CLASSES];
    __shared__ float bs[N_CLASSES];
    int tid = threadIdx.x;
    for (int i = tid; i < HIDDEN * N_CLASSES; i += 256) Ws[i] = w[i];
    if (tid < N_CLASSES) bs[tid] = b[tid];
    __syncthreads();
    int node = blockIdx.x * 16 + (tid >> 4);
    int c = tid & 15;
    const __half* hr = h + (long)node * HIDDEN;
    float acc = bs[c];
#pragma unroll
    for (int k = 0; k < HIDDEN; ++k)
        acc = fmaf(__half2float(hr[k]), Ws[k * N_CLASSES + c], acc);
    float m = acc;
#pragma unroll
    for (int off = 8; off; off >>= 1) m = fmaxf(m, __shfl_xor(m, off, 16));
    float ex = expf(acc - m);
    float s = ex;
#pragma unroll
    for (int off = 8; off; off >>= 1) s += __shfl_xor(s, off, 16);
    out[(long)node * N_CLASSES + c] = ex / s;
}

extern "C" void kernel_launch(void* const* d_in, const int* in_sizes, int n_in,
                              void* d_out, int out_size, void* d_ws, size_t ws_size,
                              hipStream_t stream) {
    const float* x    = (const float*)d_in[0];
    const int*   ei   = (const int*)d_in[1];
    const float* W1   = (const float*)d_in[2];
    const float* b1   = (const float*)d_in[3];
    const float* W2   = (const float*)d_in[4];
    const float* b2   = (const float*)d_in[5];
    const float* Wout = (const float*)d_in[6];
    const float* bout = (const float*)d_in[7];
    float* out = (float*)d_out;

    char* ws = (char*)d_ws;
    int2*   rse     = (int2*)ws;                       ws += 400128;   // 50000 int2
    float*  dinv    = (float*)ws;                      ws += 200192;   // 50000 f32
    int*    tileCur = (int*)ws;                        ws += 1024;
    int*    csr     = (int*)ws;                        ws += (size_t)NBLK_NODE * TCAP * 4;  // 6.42 MB
    char*   slotA   = ws;                              ws += 6553600;  // max(binned, bufA)
    __half* bufB    = (__half*)ws;
    int*    binned  = (int*)slotA;        // dies before k_mm<128> writes bufA
    __half* bufA    = (__half*)slotA;

    const int NB_MM = (N_NODES + 63) / 64;        // 782
    const int NB_E16 = (N_EDGES + 4095) / 4096;   // 196

    // ---- CSR build: bucketed partition -> counting sort (+deg/dinv/rse) ----
    k_init<<<1, 256, 0, stream>>>(tileCur);
    k_part<<<NB_E16, 256, 0, stream>>>(ei, tileCur, binned);
    k_finesort<<<NBLK_NODE, 256, 0, stream>>>(binned, tileCur, csr, rse, dinv);

    // ---- layer 1 (mm output pre-scaled by dinv; gather is a pure row-sum) ----
    k_mm<N_FEAT, float><<<NB_MM, 256, 0, stream>>>(x, W1, dinv, bufA);
    k_gather<<<N_NODES / 4, 256, 0, stream>>>(bufA, csr, rse, dinv, b1, bufB);

    // ---- layer 2 ----
    k_mm<HIDDEN, __half><<<NB_MM, 256, 0, stream>>>(bufB, W2, dinv, bufA);
    k_gather<<<N_NODES / 4, 256, 0, stream>>>(bufA, csr, rse, dinv, b2, bufB);

    // ---- output layer + softmax ----
    k_out<<<N_NODES / 16, 256, 0, stream>>>(bufB, Wout, bout, out);
}